// Round 10
// baseline (621.338 us; speedup 1.0000x reference)
//
#include <hip/hip_runtime.h>
#include <hip/hip_bf16.h>

// GraphSAGE 2-layer. ATTRIBUTION ROUND: identical to R8 except gemm_big is
// dispatched 3x (idempotent). dur_us = base + 2*T(gemm_big_warm), with
// base + T = 300.8 us known from R8 -> T measured directly.

typedef __attribute__((ext_vector_type(8))) __bf16 bf16x8;
typedef __attribute__((ext_vector_type(4))) float f32x4;

constexpr int K1 = 1433;
constexpr int KP1 = 1536;  // B pad (bf16): no B guards anywhere
constexpr int BK = 32;     // k per step
constexpr int NS = 45;     // ceil(1433/32); k>=1433 contributes A*0 via B pad
constexpr int BM = 128;    // rows per block

__device__ __forceinline__ void gload_lds16(const void* g, void* l) {
  __builtin_amdgcn_global_load_lds(
      reinterpret_cast<const __attribute__((address_space(1))) void*>(
          reinterpret_cast<uintptr_t>(g)),
      reinterpret_cast<__attribute__((address_space(3))) void*>(
          reinterpret_cast<uintptr_t>(l)),
      16, 0, 0);
}

__device__ __forceinline__ bf16x8 cvt8(const float4 lo, const float4 hi) {
  bf16x8 r;
  r[0] = (__bf16)lo.x; r[1] = (__bf16)lo.y;
  r[2] = (__bf16)lo.z; r[3] = (__bf16)lo.w;
  r[4] = (__bf16)hi.x; r[5] = (__bf16)hi.y;
  r[6] = (__bf16)hi.z; r[7] = (__bf16)hi.w;
  return r;
}

// Convert [W_l; W_r] (each 32 x K fp32) into WB[64][KP] bf16, zero-padded.
__global__ __launch_bounds__(256) void conv_w(const float* __restrict__ Wl,
                                              const float* __restrict__ Wr,
                                              __bf16* __restrict__ out, int K,
                                              int KP) {
  const int t = blockIdx.x * 256 + threadIdx.x;
  if (t >= 64 * KP) return;
  const int c = t / KP, k = t - c * KP;
  float v = 0.0f;
  if (k < K) v = (c < 32) ? Wl[(long)c * K + k] : Wr[(long)(c - 32) * K + k];
  out[t] = (__bf16)v;
}

// Y[N][64] = X[N][1433] @ WB[64][1536]^T.  (R8 kernel, unchanged.)
__global__ __launch_bounds__(256) void gemm_big(const float* __restrict__ X,
                                                const __bf16* __restrict__ WB,
                                                float* __restrict__ Y,
                                                int Nrows) {
  __shared__ float ldsA[2][BM][BK];      // 2 x 16 KB
  __shared__ __bf16 ldsB[2][64][BK];     // 2 x 4 KB
  const int tid = threadIdx.x;
  const int w = tid >> 6, l = tid & 63;
  const int lr = l & 15, lg = l >> 4;
  const int row0 = blockIdx.x * BM;

  const int aRowIn = (l >> 3);            // 0..7
  const int aChunk = (l & 7) ^ aRowIn;    // swizzled 16B chunk
  long aRow[4];
#pragma unroll
  for (int i = 0; i < 4; ++i) {
    long r = (long)row0 + w * 32 + i * 8 + aRowIn;
    if (r >= Nrows) r = Nrows - 1;
    aRow[i] = r;
  }
  const float* const pAmax = X + (size_t)Nrows * K1 - 4;  // clamp: stay in buf
  const int bRow = w * 16 + (l >> 2);
  const int bChunk = (l & 3) ^ ((l >> 3) & 3);
  const __bf16* const pB0 = WB + (long)bRow * KP1 + bChunk * 8;

  auto stage = [&](int s, int buf) {
    const int k0 = s * BK;
#pragma unroll
    for (int i = 0; i < 4; ++i) {
      const float* g = X + aRow[i] * K1 + k0 + aChunk * 4;
      if (g > pAmax) g = pAmax;  // finite garbage * B-zero-pad = 0
      gload_lds16(g, &ldsA[buf][w * 32 + i * 8][0]);
    }
    gload_lds16(pB0 + k0, &ldsB[buf][w * 16][0]);
  };

  f32x4 acc[2][4];
#pragma unroll
  for (int t = 0; t < 2; ++t)
#pragma unroll
    for (int j = 0; j < 4; ++j) acc[t][j] = (f32x4){0.f, 0.f, 0.f, 0.f};

  const int swzA = lr & 7;          // row&7 for this lane's A-frag rows
  const int swzB = (lr >> 1) & 3;   // (row>>1)&3 for this lane's B-frag rows

  stage(0, 0);
#pragma unroll 1
  for (int s = 0; s < NS; ++s) {
    const int buf = s & 1;
    if (s + 1 < NS) {
      stage(s + 1, buf ^ 1);
      asm volatile("s_waitcnt vmcnt(5)" ::: "memory");
    } else {
      asm volatile("s_waitcnt vmcnt(0)" ::: "memory");
    }
    __builtin_amdgcn_s_barrier();
    __builtin_amdgcn_sched_barrier(0);
    bf16x8 bfrag[4];
#pragma unroll
    for (int ct = 0; ct < 4; ++ct) {
      const int br = ct * 16 + lr;
      bfrag[ct] = *reinterpret_cast<const bf16x8*>(
          &ldsB[buf][br][(lg ^ swzB) * 8]);
    }
#pragma unroll
    for (int t = 0; t < 2; ++t) {
      const int fr = w * 32 + t * 16 + lr;
      const float4 u = *reinterpret_cast<const float4*>(
          &ldsA[buf][fr][((lg * 2 + 0) ^ swzA) * 4]);
      const float4 v = *reinterpret_cast<const float4*>(
          &ldsA[buf][fr][((lg * 2 + 1) ^ swzA) * 4]);
      const bf16x8 af = cvt8(u, v);
#pragma unroll
      for (int ct = 0; ct < 4; ++ct)
        acc[t][ct] =
            __builtin_amdgcn_mfma_f32_16x16x32_bf16(af, bfrag[ct], acc[t][ct], 0, 0, 0);
    }
    __builtin_amdgcn_sched_barrier(0);
    __builtin_amdgcn_s_barrier();
  }

#pragma unroll
  for (int t = 0; t < 2; ++t) {
#pragma unroll
    for (int j = 0; j < 4; ++j) {
      const long R = (long)row0 + w * 32 + t * 16 + lg * 4 + j;
      if (R < Nrows) {
#pragma unroll
        for (int ct = 0; ct < 4; ++ct)
          Y[R * 64 + ct * 16 + lr] = acc[t][ct][j];
      }
    }
  }
}

// Y[N][64] = X[N][32] @ WB[64][32]^T, single k-step.
__global__ __launch_bounds__(256) void gemm_small(const float* __restrict__ X,
                                                  const __bf16* __restrict__ WB,
                                                  float* __restrict__ Y,
                                                  int Nrows) {
  const int tid = threadIdx.x;
  const int w = tid >> 6, l = tid & 63;
  const int lr = l & 15, lg = l >> 4;
  const long rowbase = (long)blockIdx.x * 64 + (long)w * 16;
  long r0 = rowbase + lr;
  if (r0 >= Nrows) r0 = Nrows - 1;
  const float* px = X + r0 * 32 + lg * 8;
  const __bf16* pw = WB + lr * 32 + lg * 8;

  const float4 lo = *reinterpret_cast<const float4*>(px);
  const float4 hi = *reinterpret_cast<const float4*>(px + 4);
  const bf16x8 af = cvt8(lo, hi);
  f32x4 acc[4];
#pragma unroll
  for (int j = 0; j < 4; ++j) acc[j] = (f32x4){0.f, 0.f, 0.f, 0.f};
#pragma unroll
  for (int t = 0; t < 4; ++t) {
    const bf16x8 bf = *reinterpret_cast<const bf16x8*>(pw + t * 16 * 32);
    acc[t] = __builtin_amdgcn_mfma_f32_16x16x32_bf16(af, bf, acc[t], 0, 0, 0);
  }
#pragma unroll
  for (int j = 0; j < 4; ++j) {
    const long R = rowbase + lg * 4 + j;
    if (R < Nrows) {
#pragma unroll
      for (int ct = 0; ct < 4; ++ct) Y[R * 64 + ct * 16 + lr] = acc[ct][j];
    }
  }
}

// ---------------- CSR build: counting sort edges by tgt ----------------

__global__ __launch_bounds__(256) void hist_deg(const int* __restrict__ ei,
                                                int* __restrict__ deg, int E) {
  const int e = blockIdx.x * 256 + threadIdx.x;
  if (e < E) atomicAdd(&deg[ei[E + e]], 1);
}

__global__ __launch_bounds__(256) void scan_tilesum(const int* __restrict__ deg,
                                                    int* __restrict__ tileSum,
                                                    int n) {
  __shared__ int s[256];
  const int b = blockIdx.x, t = threadIdx.x;
  const int base = b * 2048 + t * 8;
  int v = 0;
#pragma unroll
  for (int j = 0; j < 8; ++j) {
    const int i = base + j;
    if (i < n) v += deg[i];
  }
  s[t] = v;
  __syncthreads();
  for (int d = 128; d > 0; d >>= 1) {
    if (t < d) s[t] += s[t + d];
    __syncthreads();
  }
  if (t == 0) tileSum[b] = s[0];
}

__global__ __launch_bounds__(64) void scan_tileoff(const int* __restrict__ tileSum,
                                                   int* __restrict__ tileOff,
                                                   int nT) {
  const int l = threadIdx.x;
  const int v = (l < nT) ? tileSum[l] : 0;
  int inc = v;
#pragma unroll
  for (int d = 1; d < 64; d <<= 1) {
    const int o = __shfl_up(inc, d);
    if (l >= d) inc += o;
  }
  if (l < nT) tileOff[l] = inc - v;
}

__global__ __launch_bounds__(256) void scan_offsets(const int* __restrict__ deg,
                                                    const int* __restrict__ tileOff,
                                                    int* __restrict__ off, int n) {
  __shared__ int warpTot[4];
  const int b = blockIdx.x, t = threadIdx.x;
  const int base = b * 2048 + t * 8;
  int v[8];
  int s = 0;
#pragma unroll
  for (int j = 0; j < 8; ++j) {
    const int i = base + j;
    v[j] = (i < n) ? deg[i] : 0;
    s += v[j];
  }
  const int l = t & 63, w = t >> 6;
  int inc = s;
#pragma unroll
  for (int d = 1; d < 64; d <<= 1) {
    const int o = __shfl_up(inc, d);
    if (l >= d) inc += o;
  }
  if (l == 63) warpTot[w] = inc;
  __syncthreads();
  int wo = 0;
  for (int k = 0; k < w; ++k) wo += warpTot[k];
  int ex = wo + (inc - s) + tileOff[b];
#pragma unroll
  for (int j = 0; j < 8; ++j) {
    const int i = base + j;
    if (i < n) {
      off[i] = ex;
      ex += v[j];
    }
  }
}

__global__ __launch_bounds__(256) void scatter_src(const int* __restrict__ ei,
                                                   const int* __restrict__ off,
                                                   int* __restrict__ fill,
                                                   int* __restrict__ ssrc,
                                                   int E) {
  const int e = blockIdx.x * 256 + threadIdx.x;
  if (e < E) {
    const int t = ei[E + e];
    const int p = off[t] + atomicAdd(&fill[t], 1);
    ssrc[p] = ei[e];
  }
}

// ---------------- fused aggregation ----------------
template <int FINAL>
__global__ __launch_bounds__(256) void agg_fused(
    const int* __restrict__ off, const int* __restrict__ deg,
    const int* __restrict__ ssrc, const float* __restrict__ Y,
    const float* __restrict__ bias, float* __restrict__ out, int N) {
  const int t = blockIdx.x * 256 + threadIdx.x;
  const int i = t >> 5, c = t & 31;
  if (i >= N) return;
  const int st = off[i], d = deg[i];
  float acc = 0.0f;
  int e = 0;
  for (; e + 4 <= d; e += 4) {
    const int s0 = ssrc[st + e + 0];
    const int s1 = ssrc[st + e + 1];
    const int s2 = ssrc[st + e + 2];
    const int s3 = ssrc[st + e + 3];
    acc += Y[(long)s0 * 64 + c] + Y[(long)s1 * 64 + c] +
           Y[(long)s2 * 64 + c] + Y[(long)s3 * 64 + c];
  }
  for (; e < d; ++e) acc += Y[(long)ssrc[st + e] * 64 + c];
  const float mean = acc / fmaxf((float)d, 1.0f);
  float v = mean + bias[c] + Y[(long)i * 64 + 32 + c];
  if (FINAL) {
    v = fmaxf(v, 0.0f);
    float m = v;
#pragma unroll
    for (int dd = 16; dd >= 1; dd >>= 1) m = fmaxf(m, __shfl_xor(m, dd));
    const float ex = __expf(v - m);
    float s = ex;
#pragma unroll
    for (int dd = 16; dd >= 1; dd >>= 1) s += __shfl_xor(s, dd);
    out[(long)i * 32 + c] = (v - m) - __logf(s);
  } else {
    out[(long)i * 32 + c] = v;
  }
}

extern "C" void kernel_launch(void* const* d_in, const int* in_sizes, int n_in,
                              void* d_out, int out_size, void* d_ws,
                              size_t ws_size, hipStream_t stream) {
  const float* x = (const float*)d_in[0];
  const int* ei = (const int*)d_in[1];
  const float* W1l = (const float*)d_in[2];
  const float* b1l = (const float*)d_in[3];
  const float* W1r = (const float*)d_in[4];
  const float* W2l = (const float*)d_in[5];
  const float* b2l = (const float*)d_in[6];
  const float* W2r = (const float*)d_in[7];
  float* out = (float*)d_out;

  const int N = in_sizes[0] / K1;
  const int E = in_sizes[1] / 2;
  const int nTiles = (N + 2047) / 2048;

  char* ws = (char*)d_ws;
  size_t o = 0;
  auto alloc = [&](size_t bytes) {
    void* p = ws + o;
    o += (bytes + 255) & ~(size_t)255;
    return p;
  };
  float* ycomb = (float*)alloc((size_t)N * 64 * 4);
  float* h = (float*)alloc((size_t)N * 32 * 4);
  __bf16* wb1 = (__bf16*)alloc((size_t)64 * KP1 * 2);
  __bf16* wb2 = (__bf16*)alloc((size_t)64 * 32 * 2);
  int* deg = (int*)alloc((size_t)N * 4);
  int* off = (int*)alloc((size_t)N * 4);
  int* fill = (int*)alloc((size_t)N * 4);
  int* ssrc = (int*)alloc((size_t)E * 4);
  int* tileSum = (int*)alloc(64 * 4);
  int* tileOff = (int*)alloc(64 * 4);

  conv_w<<<(64 * KP1 + 255) / 256, 256, 0, stream>>>(W1l, W1r, wb1, K1, KP1);
  conv_w<<<(64 * 32 + 255) / 256, 256, 0, stream>>>(W2l, W2r, wb2, 32, 32);
  (void)hipMemsetAsync(deg, 0, (size_t)N * 4, stream);
  (void)hipMemsetAsync(fill, 0, (size_t)N * 4, stream);
  hist_deg<<<(E + 255) / 256, 256, 0, stream>>>(ei, deg, E);
  scan_tilesum<<<nTiles, 256, 0, stream>>>(deg, tileSum, N);
  scan_tileoff<<<1, 64, 0, stream>>>(tileSum, tileOff, nTiles);
  scan_offsets<<<nTiles, 256, 0, stream>>>(deg, tileOff, off, N);
  scatter_src<<<(E + 255) / 256, 256, 0, stream>>>(ei, off, fill, ssrc, E);

  // Layer 1 — gemm_big dispatched 3x (idempotent) for marginal-cost timing.
  gemm_big<<<(N + BM - 1) / BM, 256, 0, stream>>>(x, wb1, ycomb, N);
  gemm_big<<<(N + BM - 1) / BM, 256, 0, stream>>>(x, wb1, ycomb, N);
  gemm_big<<<(N + BM - 1) / BM, 256, 0, stream>>>(x, wb1, ycomb, N);
  agg_fused<0><<<(N * 32 + 255) / 256, 256, 0, stream>>>(off, deg, ssrc, ycomb,
                                                         b1l, h, N);
  // Layer 2
  gemm_small<<<(N + 63) / 64, 256, 0, stream>>>(h, wb2, ycomb, N);
  agg_fused<1><<<(N * 32 + 255) / 256, 256, 0, stream>>>(off, deg, ssrc, ycomb,
                                                         b2l, out, N);
}

// Round 11
// 287.076 us; speedup vs baseline: 2.1644x; 2.1644x over previous
//
#include <hip/hip_runtime.h>
#include <hip/hip_bf16.h>

// GraphSAGE 2-layer. Project-then-aggregate (aggregation is linear):
//   ycomb = x @ [W1l|W1r]^T      (bf16 MFMA, gload_lds, counted vmcnt — R8)
//   CSR build (counting sort), then per layer:
//   L1: agg_gemm2 = [csr_mean + bias + self] -> h(LDS,bf16) -> h@[W2l|W2r]^T
//   L2: agg_fused = csr_mean + bias + self -> relu -> log_softmax -> out
// Attribution (R10): gemm_big = 160 us, base = 140 us. This round cuts base:
// 13 -> 9 dispatches, h round-trip eliminated, gemm_big untouched.

typedef __attribute__((ext_vector_type(8))) __bf16 bf16x8;
typedef __attribute__((ext_vector_type(4))) float f32x4;

constexpr int K1 = 1433;
constexpr int KP1 = 1536;  // B pad (bf16): no B guards anywhere
constexpr int BK = 32;     // k per step
constexpr int NS = 45;     // ceil(1433/32); k>=1433 contributes A*0 via B pad
constexpr int BM = 128;    // rows per block

__device__ __forceinline__ void gload_lds16(const void* g, void* l) {
  __builtin_amdgcn_global_load_lds(
      reinterpret_cast<const __attribute__((address_space(1))) void*>(
          reinterpret_cast<uintptr_t>(g)),
      reinterpret_cast<__attribute__((address_space(3))) void*>(
          reinterpret_cast<uintptr_t>(l)),
      16, 0, 0);
}

__device__ __forceinline__ bf16x8 cvt8(const float4 lo, const float4 hi) {
  bf16x8 r;
  r[0] = (__bf16)lo.x; r[1] = (__bf16)lo.y;
  r[2] = (__bf16)lo.z; r[3] = (__bf16)lo.w;
  r[4] = (__bf16)hi.x; r[5] = (__bf16)hi.y;
  r[6] = (__bf16)hi.z; r[7] = (__bf16)hi.w;
  return r;
}

// Both weight conversions in one dispatch.
__global__ __launch_bounds__(256) void conv_w2(const float* __restrict__ W1l,
                                               const float* __restrict__ W1r,
                                               const float* __restrict__ W2l,
                                               const float* __restrict__ W2r,
                                               __bf16* __restrict__ wb1,
                                               __bf16* __restrict__ wb2) {
  const int t = blockIdx.x * 256 + threadIdx.x;
  if (t < 64 * KP1) {
    const int c = t / KP1, k = t - c * KP1;
    float v = 0.0f;
    if (k < K1)
      v = (c < 32) ? W1l[(long)c * K1 + k] : W1r[(long)(c - 32) * K1 + k];
    wb1[t] = (__bf16)v;
  } else {
    const int u = t - 64 * KP1;
    if (u < 64 * 32) {
      const int c = u >> 5, k = u & 31;
      const float v = (c < 32) ? W2l[c * 32 + k] : W2r[(c - 32) * 32 + k];
      wb2[u] = (__bf16)v;
    }
  }
}

// Y[N][64] = X[N][1433] @ WB[64][1536]^T.  (R8 kernel, byte-identical.)
__global__ __launch_bounds__(256) void gemm_big(const float* __restrict__ X,
                                                const __bf16* __restrict__ WB,
                                                float* __restrict__ Y,
                                                int Nrows) {
  __shared__ float ldsA[2][BM][BK];      // 2 x 16 KB
  __shared__ __bf16 ldsB[2][64][BK];     // 2 x 4 KB
  const int tid = threadIdx.x;
  const int w = tid >> 6, l = tid & 63;
  const int lr = l & 15, lg = l >> 4;
  const int row0 = blockIdx.x * BM;

  const int aRowIn = (l >> 3);
  const int aChunk = (l & 7) ^ aRowIn;
  long aRow[4];
#pragma unroll
  for (int i = 0; i < 4; ++i) {
    long r = (long)row0 + w * 32 + i * 8 + aRowIn;
    if (r >= Nrows) r = Nrows - 1;
    aRow[i] = r;
  }
  const float* const pAmax = X + (size_t)Nrows * K1 - 4;
  const int bRow = w * 16 + (l >> 2);
  const int bChunk = (l & 3) ^ ((l >> 3) & 3);
  const __bf16* const pB0 = WB + (long)bRow * KP1 + bChunk * 8;

  auto stage = [&](int s, int buf) {
    const int k0 = s * BK;
#pragma unroll
    for (int i = 0; i < 4; ++i) {
      const float* g = X + aRow[i] * K1 + k0 + aChunk * 4;
      if (g > pAmax) g = pAmax;
      gload_lds16(g, &ldsA[buf][w * 32 + i * 8][0]);
    }
    gload_lds16(pB0 + k0, &ldsB[buf][w * 16][0]);
  };

  f32x4 acc[2][4];
#pragma unroll
  for (int t = 0; t < 2; ++t)
#pragma unroll
    for (int j = 0; j < 4; ++j) acc[t][j] = (f32x4){0.f, 0.f, 0.f, 0.f};

  const int swzA = lr & 7;
  const int swzB = (lr >> 1) & 3;

  stage(0, 0);
#pragma unroll 1
  for (int s = 0; s < NS; ++s) {
    const int buf = s & 1;
    if (s + 1 < NS) {
      stage(s + 1, buf ^ 1);
      asm volatile("s_waitcnt vmcnt(5)" ::: "memory");
    } else {
      asm volatile("s_waitcnt vmcnt(0)" ::: "memory");
    }
    __builtin_amdgcn_s_barrier();
    __builtin_amdgcn_sched_barrier(0);
    bf16x8 bfrag[4];
#pragma unroll
    for (int ct = 0; ct < 4; ++ct) {
      const int br = ct * 16 + lr;
      bfrag[ct] = *reinterpret_cast<const bf16x8*>(
          &ldsB[buf][br][(lg ^ swzB) * 8]);
    }
#pragma unroll
    for (int t = 0; t < 2; ++t) {
      const int fr = w * 32 + t * 16 + lr;
      const float4 u = *reinterpret_cast<const float4*>(
          &ldsA[buf][fr][((lg * 2 + 0) ^ swzA) * 4]);
      const float4 v = *reinterpret_cast<const float4*>(
          &ldsA[buf][fr][((lg * 2 + 1) ^ swzA) * 4]);
      const bf16x8 af = cvt8(u, v);
#pragma unroll
      for (int ct = 0; ct < 4; ++ct)
        acc[t][ct] =
            __builtin_amdgcn_mfma_f32_16x16x32_bf16(af, bfrag[ct], acc[t][ct], 0, 0, 0);
    }
    __builtin_amdgcn_sched_barrier(0);
    __builtin_amdgcn_s_barrier();
  }

#pragma unroll
  for (int t = 0; t < 2; ++t) {
#pragma unroll
    for (int j = 0; j < 4; ++j) {
      const long R = (long)row0 + w * 32 + t * 16 + lg * 4 + j;
      if (R < Nrows) {
#pragma unroll
        for (int ct = 0; ct < 4; ++ct)
          Y[R * 64 + ct * 16 + lr] = acc[t][ct][j];
      }
    }
  }
}

// ---------------- CSR build: counting sort edges by tgt ----------------

__global__ __launch_bounds__(256) void hist_deg(const int* __restrict__ ei,
                                                int* __restrict__ deg, int E) {
  const int e = blockIdx.x * 256 + threadIdx.x;
  if (e < E) atomicAdd(&deg[ei[E + e]], 1);
}

__global__ __launch_bounds__(256) void scan_tilesum(const int* __restrict__ deg,
                                                    int* __restrict__ tileSum,
                                                    int n) {
  __shared__ int s[256];
  const int b = blockIdx.x, t = threadIdx.x;
  const int base = b * 2048 + t * 8;
  int v = 0;
#pragma unroll
  for (int j = 0; j < 8; ++j) {
    const int i = base + j;
    if (i < n) v += deg[i];
  }
  s[t] = v;
  __syncthreads();
  for (int d = 128; d > 0; d >>= 1) {
    if (t < d) s[t] += s[t + d];
    __syncthreads();
  }
  if (t == 0) tileSum[b] = s[0];
}

// Per-tile exclusive scan; tile offset computed in-kernel (wave-reduce over
// the <=64 preceding tile sums) — scan_tileoff dispatch eliminated.
__global__ __launch_bounds__(256) void scan_offsets(const int* __restrict__ deg,
                                                    const int* __restrict__ tileSum,
                                                    int* __restrict__ off,
                                                    int n, int nT) {
  __shared__ int warpTot[4];
  __shared__ int tileOffS;
  const int b = blockIdx.x, t = threadIdx.x;
  if (t < 64) {
    int v = (t < b && t < nT) ? tileSum[t] : 0;
#pragma unroll
    for (int d = 1; d < 64; d <<= 1) v += __shfl_xor(v, d);
    if (t == 0) tileOffS = v;
  }
  const int base = b * 2048 + t * 8;
  int v[8];
  int s = 0;
#pragma unroll
  for (int j = 0; j < 8; ++j) {
    const int i = base + j;
    v[j] = (i < n) ? deg[i] : 0;
    s += v[j];
  }
  const int l = t & 63, w = t >> 6;
  int inc = s;
#pragma unroll
  for (int d = 1; d < 64; d <<= 1) {
    const int o = __shfl_up(inc, d);
    if (l >= d) inc += o;
  }
  if (l == 63) warpTot[w] = inc;
  __syncthreads();
  int wo = 0;
  for (int k = 0; k < w; ++k) wo += warpTot[k];
  int ex = wo + (inc - s) + tileOffS;
#pragma unroll
  for (int j = 0; j < 8; ++j) {
    const int i = base + j;
    if (i < n) {
      off[i] = ex;
      ex += v[j];
    }
  }
}

__global__ __launch_bounds__(256) void scatter_src(const int* __restrict__ ei,
                                                   const int* __restrict__ off,
                                                   int* __restrict__ fill,
                                                   int* __restrict__ ssrc,
                                                   int E) {
  const int e = blockIdx.x * 256 + threadIdx.x;
  if (e < E) {
    const int t = ei[E + e];
    const int p = off[t] + atomicAdd(&fill[t], 1);
    ssrc[p] = ei[e];
  }
}

// ---------- fused layer-1 tail: agg -> h (LDS bf16) -> h @ W2^T ----------
// Block = 64 nodes. Phase 1: 256 threads gather csr_mean for (node, c) pairs
// (8 nodes/thread), h = mean + b1[c] + Y[i][32+c], stored bf16 in LDS.
// Phase 2: 4 waves MFMA the 64x32 h-tile against WB2 (K=32) -> Y2[64][64].
__global__ __launch_bounds__(256) void agg_gemm2(
    const int* __restrict__ off, const int* __restrict__ deg,
    const int* __restrict__ ssrc, const float* __restrict__ Y,
    const float* __restrict__ b1, const __bf16* __restrict__ WB2,
    float* __restrict__ Y2, int N) {
  __shared__ __bf16 hs[64][40];  // 80-B row stride: 16-B aligned reads
  const int tid = threadIdx.x;
  const int nb0 = blockIdx.x * 64;
  const int c = tid & 31, r8 = tid >> 5;  // r8 in 0..7

  int stA[8], dgA[8];
#pragma unroll
  for (int j = 0; j < 8; ++j) {
    const int i = nb0 + r8 * 8 + j;
    stA[j] = (i < N) ? off[i] : 0;
    dgA[j] = (i < N) ? deg[i] : 0;
  }
#pragma unroll 1
  for (int j = 0; j < 8; ++j) {
    const int i = nb0 + r8 * 8 + j;
    float hv = 0.0f;
    if (i < N) {
      const int st = stA[j], d = dgA[j];
      float acc = 0.0f;
      int e = 0;
      for (; e + 4 <= d; e += 4) {
        const int s0 = ssrc[st + e + 0];
        const int s1 = ssrc[st + e + 1];
        const int s2 = ssrc[st + e + 2];
        const int s3 = ssrc[st + e + 3];
        acc += Y[(long)s0 * 64 + c] + Y[(long)s1 * 64 + c] +
               Y[(long)s2 * 64 + c] + Y[(long)s3 * 64 + c];
      }
      for (; e < d; ++e) acc += Y[(long)ssrc[st + e] * 64 + c];
      hv = acc / fmaxf((float)d, 1.0f) + b1[c] + Y[(long)i * 64 + 32 + c];
    }
    hs[r8 * 8 + j][c] = (__bf16)hv;
  }
  __syncthreads();

  // ---- MFMA phase (mirrors gemm_small's layout exactly) ----
  const int w = tid >> 6, l = tid & 63;
  const int lr = l & 15, lg = l >> 4;
  const bf16x8 af = *reinterpret_cast<const bf16x8*>(&hs[w * 16 + lr][lg * 8]);
  f32x4 acc4[4];
#pragma unroll
  for (int j = 0; j < 4; ++j) acc4[j] = (f32x4){0.f, 0.f, 0.f, 0.f};
#pragma unroll
  for (int ct = 0; ct < 4; ++ct) {
    const bf16x8 bf = *reinterpret_cast<const bf16x8*>(
        WB2 + (ct * 16 + lr) * 32 + lg * 8);
    acc4[ct] = __builtin_amdgcn_mfma_f32_16x16x32_bf16(af, bf, acc4[ct], 0, 0, 0);
  }
#pragma unroll
  for (int j = 0; j < 4; ++j) {
    const long R = (long)nb0 + w * 16 + lg * 4 + j;
    if (R < N) {
#pragma unroll
      for (int ct = 0; ct < 4; ++ct) Y2[R * 64 + ct * 16 + lr] = acc4[ct][j];
    }
  }
}

// ---------------- layer-2 tail: agg + relu + log_softmax ----------------
__global__ __launch_bounds__(256) void agg_final(
    const int* __restrict__ off, const int* __restrict__ deg,
    const int* __restrict__ ssrc, const float* __restrict__ Y,
    const float* __restrict__ bias, float* __restrict__ out, int N) {
  const int t = blockIdx.x * 256 + threadIdx.x;
  const int i = t >> 5, c = t & 31;
  if (i >= N) return;
  const int st = off[i], d = deg[i];
  float acc = 0.0f;
  int e = 0;
  for (; e + 4 <= d; e += 4) {
    const int s0 = ssrc[st + e + 0];
    const int s1 = ssrc[st + e + 1];
    const int s2 = ssrc[st + e + 2];
    const int s3 = ssrc[st + e + 3];
    acc += Y[(long)s0 * 64 + c] + Y[(long)s1 * 64 + c] +
           Y[(long)s2 * 64 + c] + Y[(long)s3 * 64 + c];
  }
  for (; e < d; ++e) acc += Y[(long)ssrc[st + e] * 64 + c];
  const float mean = acc / fmaxf((float)d, 1.0f);
  float v = mean + bias[c] + Y[(long)i * 64 + 32 + c];
  v = fmaxf(v, 0.0f);
  float m = v;
#pragma unroll
  for (int dd = 16; dd >= 1; dd >>= 1) m = fmaxf(m, __shfl_xor(m, dd));
  const float ex = __expf(v - m);
  float s = ex;
#pragma unroll
  for (int dd = 16; dd >= 1; dd >>= 1) s += __shfl_xor(s, dd);
  out[(long)i * 32 + c] = (v - m) - __logf(s);
}

extern "C" void kernel_launch(void* const* d_in, const int* in_sizes, int n_in,
                              void* d_out, int out_size, void* d_ws,
                              size_t ws_size, hipStream_t stream) {
  const float* x = (const float*)d_in[0];
  const int* ei = (const int*)d_in[1];
  const float* W1l = (const float*)d_in[2];
  const float* b1l = (const float*)d_in[3];
  const float* W1r = (const float*)d_in[4];
  const float* W2l = (const float*)d_in[5];
  const float* b2l = (const float*)d_in[6];
  const float* W2r = (const float*)d_in[7];
  float* out = (float*)d_out;

  const int N = in_sizes[0] / K1;
  const int E = in_sizes[1] / 2;
  const int nTiles = (N + 2047) / 2048;

  char* ws = (char*)d_ws;
  size_t o = 0;
  auto alloc = [&](size_t bytes) {
    void* p = ws + o;
    o += (bytes + 255) & ~(size_t)255;
    return p;
  };
  float* ycomb1 = (float*)alloc((size_t)N * 64 * 4);
  float* ycomb2 = (float*)alloc((size_t)N * 64 * 4);
  __bf16* wb1 = (__bf16*)alloc((size_t)64 * KP1 * 2);
  __bf16* wb2 = (__bf16*)alloc((size_t)64 * 32 * 2);
  int* deg = (int*)alloc((size_t)2 * N * 4);  // deg | fill contiguous
  int* fill = deg + N;
  int* off = (int*)alloc((size_t)N * 4);
  int* ssrc = (int*)alloc((size_t)E * 4);
  int* tileSum = (int*)alloc(64 * 4);

  // 1 conversion dispatch + 1 memset + 4 CSR dispatches
  conv_w2<<<(64 * KP1 + 64 * 32 + 255) / 256, 256, 0, stream>>>(
      W1l, W1r, W2l, W2r, wb1, wb2);
  (void)hipMemsetAsync(deg, 0, (size_t)2 * N * 4, stream);
  hist_deg<<<(E + 255) / 256, 256, 0, stream>>>(ei, deg, E);
  scan_tilesum<<<nTiles, 256, 0, stream>>>(deg, tileSum, N);
  scan_offsets<<<nTiles, 256, 0, stream>>>(deg, tileSum, off, N, nTiles);
  scatter_src<<<(E + 255) / 256, 256, 0, stream>>>(ei, off, fill, ssrc, E);

  // Layer 1 GEMM, then fused [agg+bias+self -> h -> h@W2] in one dispatch
  gemm_big<<<(N + BM - 1) / BM, 256, 0, stream>>>(x, wb1, ycomb1, N);
  agg_gemm2<<<(N + 63) / 64, 256, 0, stream>>>(off, deg, ssrc, ycomb1, b1l,
                                               wb2, ycomb2, N);
  // Layer 2 tail
  agg_final<<<(N * 32 + 255) / 256, 256, 0, stream>>>(off, deg, ssrc, ycomb2,
                                                      b2l, out, N);
}